// Round 1
// baseline (466.262 us; speedup 1.0000x reference)
//
#include <hip/hip_runtime.h>

#define BN 4
#define CIN 512
#define H1 60
#define W1 80
#define P1 4800
#define H2 30
#define W2 40
#define P2 1200
#define HID 64
#define NCLS 11
#define HF 480
#define WF 640
#define PF 307200
#define THRESH 500

// ws layout (float element offsets)
#define WT1_OFF 0                   // 512*64 transposed w1 [c][o]
#define WT2_OFF 32768               // 512*64 transposed w2
#define F2_OFF  65536               // 4*1200*64 post-relu f2, pixel-major [b][p][o]
#define L_OFF   (65536 + 307200)    // 372736: 4*4800*12 coarse logits [b][p][k], k=0..10, slot 11 = 0
#define STATS_OFF (372736 + 230400) // 603136: 4*9*5 ints {cnt,minx,miny,maxx,maxy}

// ---------------- K0: transpose weights + init bbox stats ----------------
__global__ void k0_init(const float* __restrict__ w1, const float* __restrict__ w2,
                        float* __restrict__ ws) {
    int idx = blockIdx.x * 256 + threadIdx.x;
    if (idx < 32768) {
        int c = idx >> 6, o = idx & 63;
        ws[WT1_OFF + idx] = w1[o * CIN + c];
    } else if (idx < 65536) {
        int j = idx - 32768;
        int c = j >> 6, o = j & 63;
        ws[WT2_OFF + j] = w2[o * CIN + c];
    } else if (idx < 65536 + 180) {
        int j = idx - 65536;
        int f = j % 5;
        int v = (f == 0) ? 0 : (f == 1) ? WF : (f == 2) ? HF : -1;
        ((int*)(ws + STATS_OFF))[j] = v;
    }
}

// ---------------- K1: conv2 (512->64) + relu, pixel-major out ----------------
__global__ __launch_bounds__(256) void k1_conv2(const float* __restrict__ x,
                                                const float* __restrict__ b2,
                                                float* __restrict__ ws) {
    const float* wt = ws + WT2_OFF;
    float* f2o = ws + F2_OFF;
    int blk = blockIdx.x;
    int b = blk / 38, tile = blk % 38;
    int t = threadIdx.x;
    int pl = t & 31;
    int og = t >> 5;          // 0..7, 8 outputs each
    int o0 = og * 8;
    int p = tile * 32 + pl;
    if (p >= P2) return;
    float acc[8];
#pragma unroll
    for (int i = 0; i < 8; ++i) acc[i] = 0.f;
    const float* xp = x + (size_t)b * CIN * P2 + p;
    for (int c = 0; c < CIN; ++c) {
        float xv = xp[(size_t)c * P2];
        const float4* w4 = (const float4*)(wt + c * HID + o0);
        float4 wa = w4[0], wb = w4[1];
        acc[0] = fmaf(wa.x, xv, acc[0]);
        acc[1] = fmaf(wa.y, xv, acc[1]);
        acc[2] = fmaf(wa.z, xv, acc[2]);
        acc[3] = fmaf(wa.w, xv, acc[3]);
        acc[4] = fmaf(wb.x, xv, acc[4]);
        acc[5] = fmaf(wb.y, xv, acc[5]);
        acc[6] = fmaf(wb.z, xv, acc[6]);
        acc[7] = fmaf(wb.w, xv, acc[7]);
    }
    float* out = f2o + ((size_t)b * P2 + p) * HID + o0;
#pragma unroll
    for (int i = 0; i < 8; ++i) out[i] = fmaxf(acc[i] + b2[o0 + i], 0.f);
}

// ------- K2: conv1 + relu + 2x-bilerp(f2) add + 11-ch coarse logits -------
__global__ __launch_bounds__(256) void k2_conv1(const float* __restrict__ x,
                                                const float* __restrict__ b1,
                                                const float* __restrict__ wc,
                                                const float* __restrict__ bc,
                                                float* __restrict__ ws) {
    __shared__ float gL[32 * 65];
    const float* wt = ws + WT1_OFF;
    const float* f2 = ws + F2_OFF;
    float* lout = ws + L_OFF;
    int blk = blockIdx.x;
    int b = blk / 150, tile = blk % 150;   // 150 tiles of 32 pixels
    int t = threadIdx.x;
    int pl = t & 31;
    int og = t >> 5;     // 0..7
    int o0 = og * 8;
    int p = tile * 32 + pl;   // < 4800 always

    float acc[8];
#pragma unroll
    for (int i = 0; i < 8; ++i) acc[i] = 0.f;
    const float* xp = x + (size_t)b * CIN * P1 + p;
    for (int c = 0; c < CIN; ++c) {
        float xv = xp[(size_t)c * P1];
        const float4* w4 = (const float4*)(wt + c * HID + o0);
        float4 wa = w4[0], wb = w4[1];
        acc[0] = fmaf(wa.x, xv, acc[0]);
        acc[1] = fmaf(wa.y, xv, acc[1]);
        acc[2] = fmaf(wa.z, xv, acc[2]);
        acc[3] = fmaf(wa.w, xv, acc[3]);
        acc[4] = fmaf(wb.x, xv, acc[4]);
        acc[5] = fmaf(wb.y, xv, acc[5]);
        acc[6] = fmaf(wb.z, xv, acc[6]);
        acc[7] = fmaf(wb.w, xv, acc[7]);
    }

    // 2x upsample of f2 (half-pixel bilinear, clamped) and add to relu(conv1)
    int y = p / W1, xq = p - y * W1;
    float sy = fmaf((float)y, 0.5f, -0.25f);
    float fy = floorf(sy);
    float ty = sy - fy;
    int y0 = max(0, min(H2 - 1, (int)fy));
    int y1 = max(0, min(H2 - 1, (int)fy + 1));
    float sx = fmaf((float)xq, 0.5f, -0.25f);
    float fx = floorf(sx);
    float tx = sx - fx;
    int x0 = max(0, min(W2 - 1, (int)fx));
    int x1 = max(0, min(W2 - 1, (int)fx + 1));
    float wy0 = 1.f - ty, wx0 = 1.f - tx;
    const float* f2b = f2 + (size_t)b * P2 * HID;
    const float* r00 = f2b + (y0 * W2 + x0) * HID + o0;
    const float* r01 = f2b + (y0 * W2 + x1) * HID + o0;
    const float* r10 = f2b + (y1 * W2 + x0) * HID + o0;
    const float* r11 = f2b + (y1 * W2 + x1) * HID + o0;
#pragma unroll
    for (int i = 0; i < 8; ++i) {
        float f1v = fmaxf(acc[i] + b1[o0 + i], 0.f);
        float v0 = r00[i] * wx0 + r01[i] * tx;
        float v1 = r10[i] * wx0 + r11[i] * tx;
        gL[pl * 65 + o0 + i] = f1v + (v0 * wy0 + v1 * ty);
    }
    __syncthreads();

    // coarse logits: l[p][k] = sum_o wc[k][o]*g[p][o] + bc[k]
    int p2 = t & 31;
    int kg = t >> 5;                 // k1 = kg (0..7), k2 = kg+8 (valid kg<3)
    int k2i = (kg < 3) ? kg + 8 : 8; // safe index
    float l1 = bc[kg];
    float l2 = bc[k2i];
    for (int o = 0; o < HID; ++o) {
        float gv = gL[p2 * 65 + o];
        l1 = fmaf(wc[kg * HID + o], gv, l1);
        l2 = fmaf(wc[k2i * HID + o], gv, l2);
    }
    float* lrow = lout + ((size_t)b * P1 + tile * 32 + p2) * 12;
    lrow[kg] = l1;
    if (kg < 3) lrow[kg + 8] = l2;
    else if (kg == 3) lrow[11] = 0.f;   // pad slot so K4 can float4-load
}

// ------- K4: 8x bilerp of logits + softmax + argmax + bbox stats -------
__global__ __launch_bounds__(256) void k4_main(float* __restrict__ out,
                                               float* __restrict__ ws) {
    __shared__ int s_cnt[9], s_x0[9], s_y0[9], s_x1[9], s_y1[9];
    const float* l = ws + L_OFF;
    int* stats = (int*)(ws + STATS_OFF);
    int t = threadIdx.x;
    if (t < 9) { s_cnt[t] = 0; s_x0[t] = WF; s_y0[t] = HF; s_x1[t] = -1; s_y1[t] = -1; }
    __syncthreads();

    int fl = blockIdx.x * 256 + t;         // grid exactly covers 4*307200
    int b = fl / PF;
    int r = fl - b * PF;
    int Y = r / WF;
    int X = r - Y * WF;

    float sy = fmaf((float)Y, 0.125f, -0.4375f);
    float fy = floorf(sy);
    float ty = sy - fy;
    int y0 = max(0, min(H1 - 1, (int)fy));
    int y1 = max(0, min(H1 - 1, (int)fy + 1));
    float sx = fmaf((float)X, 0.125f, -0.4375f);
    float fx = floorf(sx);
    float tx = sx - fx;
    int x0 = max(0, min(W1 - 1, (int)fx));
    int x1 = max(0, min(W1 - 1, (int)fx + 1));
    float wy0 = 1.f - ty, wx0 = 1.f - tx;

    const float* lb = l + (size_t)b * P1 * 12;
    const float4* q00 = (const float4*)(lb + (y0 * W1 + x0) * 12);
    const float4* q01 = (const float4*)(lb + (y0 * W1 + x1) * 12);
    const float4* q10 = (const float4*)(lb + (y1 * W1 + x0) * 12);
    const float4* q11 = (const float4*)(lb + (y1 * W1 + x1) * 12);
    float l00[12], l01[12], l10[12], l11[12];
#pragma unroll
    for (int j = 0; j < 3; ++j) {
        ((float4*)l00)[j] = q00[j];
        ((float4*)l01)[j] = q01[j];
        ((float4*)l10)[j] = q10[j];
        ((float4*)l11)[j] = q11[j];
    }
    float li[11];
#pragma unroll
    for (int k = 0; k < 11; ++k) {
        float v0 = l00[k] * wx0 + l01[k] * tx;
        float v1 = l10[k] * wx0 + l11[k] * tx;
        li[k] = v0 * wy0 + v1 * ty;
    }
    int am = 0;
    float bm = li[0];
#pragma unroll
    for (int k = 1; k < 11; ++k) {
        if (li[k] > bm) { bm = li[k]; am = k; }   // strict > keeps first max
    }
    float e[11];
    float s = 0.f;
#pragma unroll
    for (int k = 0; k < 11; ++k) { e[k] = __expf(li[k] - bm); s += e[k]; }
    float rs = 1.f / s;
    size_t ob = (size_t)b * NCLS * PF + r;
#pragma unroll
    for (int k = 0; k < 11; ++k) out[ob + (size_t)k * PF] = e[k] * rs;
    out[(size_t)BN * NCLS * PF + fl] = (float)am;

    if (am >= 1 && am <= 9) {
        int ci = am - 1;
        atomicAdd(&s_cnt[ci], 1);
        atomicMin(&s_x0[ci], X);
        atomicMax(&s_x1[ci], X);
        atomicMin(&s_y0[ci], Y);
        atomicMax(&s_y1[ci], Y);
    }
    __syncthreads();
    if (t < 9 && s_cnt[t] > 0) {
        int* st = stats + (b * 9 + t) * 5;
        atomicAdd(&st[0], s_cnt[t]);
        atomicMin(&st[1], s_x0[t]);
        atomicMin(&st[2], s_y0[t]);
        atomicMax(&st[3], s_x1[t]);
        atomicMax(&st[4], s_y1[t]);
    }
}

// ---------------- K5: emit bbox rows ----------------
__global__ void k5_bbx(float* __restrict__ out, const float* __restrict__ ws) {
    const int* stats = (const int*)(ws + STATS_OFF);
    int t = threadIdx.x;
    if (t >= 216) return;
    int row = t / 6, j = t - row * 6;
    int b = row / 9, c = row - b * 9;
    const int* st = stats + row * 5;
    int cnt = st[0];
    int v;
    if (cnt < THRESH) v = -1;
    else v = (j == 0) ? b
           : (j == 1) ? st[1]      // x1
           : (j == 2) ? st[2]      // y1
           : (j == 3) ? st[3]      // x2
           : (j == 4) ? st[4]      // y2
           : (c + 1);              // cls
    out[(size_t)BN * NCLS * PF + (size_t)BN * PF + t] = (float)v;
}

extern "C" void kernel_launch(void* const* d_in, const int* in_sizes, int n_in,
                              void* d_out, int out_size, void* d_ws, size_t ws_size,
                              hipStream_t stream) {
    const float* f1 = (const float*)d_in[0];
    const float* f2 = (const float*)d_in[1];
    const float* w1 = (const float*)d_in[2];
    const float* b1 = (const float*)d_in[3];
    const float* w2 = (const float*)d_in[4];
    const float* b2 = (const float*)d_in[5];
    const float* wc = (const float*)d_in[6];
    const float* bc = (const float*)d_in[7];
    float* out = (float*)d_out;
    float* ws = (float*)d_ws;

    k0_init<<<dim3(257), dim3(256), 0, stream>>>(w1, w2, ws);
    k1_conv2<<<dim3(4 * 38), dim3(256), 0, stream>>>(f2, b2, ws);
    k2_conv1<<<dim3(4 * 150), dim3(256), 0, stream>>>(f1, b1, wc, bc, ws);
    k4_main<<<dim3(4800), dim3(256), 0, stream>>>(out, ws);
    k5_bbx<<<dim3(1), dim3(256), 0, stream>>>(out, ws);
}

// Round 2
// 260.193 us; speedup vs baseline: 1.7920x; 1.7920x over previous
//
#include <hip/hip_runtime.h>

#define BN 4
#define CIN 512
#define H1 60
#define W1 80
#define P1 4800
#define H2 30
#define W2 40
#define P2 1200
#define HID 64
#define NCLS 11
#define HF 480
#define WF 640
#define PF 307200
#define THRESH 500

// ws layout (float element offsets)
#define WT1_OFF 0                   // 512*64 transposed w1 [c][o]
#define WT2_OFF 32768               // 512*64 transposed w2
#define F2_OFF  65536               // 4*1200*64 post-relu f2, pixel-major [b][p][o]
#define PART_OFF F2_OFF             // k4 bbox partials alias F2 (dead by then): 4800*45 ints
#define L_OFF   (65536 + 307200)    // 372736: 4*4800*12 coarse logits [b][p][k], k=0..10, slot 11 = 0

// ---------------- K0: transpose weights ----------------
__global__ void k0_init(const float* __restrict__ w1, const float* __restrict__ w2,
                        float* __restrict__ ws) {
    int idx = blockIdx.x * 256 + threadIdx.x;
    if (idx < 32768) {
        int c = idx >> 6, o = idx & 63;
        ws[WT1_OFF + idx] = w1[o * CIN + c];
    } else {
        int j = idx - 32768;
        int c = j >> 6, o = j & 63;
        ws[WT2_OFF + j] = w2[o * CIN + c];
    }
}

// ---------------- K1: conv2 (512->64) + relu, pixel-major out ----------------
// 512 thr = 8 px x 8 og x 8 c-chunks(64). 600 blocks -> ~18.75 waves/CU.
__global__ __launch_bounds__(512) void k1_conv2(const float* __restrict__ x,
                                                const float* __restrict__ b2,
                                                float* __restrict__ ws) {
    __shared__ float part[8][8][64];
    const float* wt = ws + WT2_OFF;
    float* f2o = ws + F2_OFF;
    int blk = blockIdx.x;
    int b = blk / 150, tile = blk % 150;
    int t = threadIdx.x;
    int pl = t & 7;
    int og = (t >> 3) & 7;
    int ch = t >> 6;            // 0..7
    int o0 = og * 8;
    int c0 = ch * 64;
    int p = tile * 8 + pl;

    float acc[8];
#pragma unroll
    for (int i = 0; i < 8; ++i) acc[i] = 0.f;
    const float* xp = x + ((size_t)b * CIN + c0) * P2 + p;
    const float* wp = wt + c0 * HID + o0;
#pragma unroll 8
    for (int c = 0; c < 64; ++c) {
        float xv = xp[(size_t)c * P2];
        float4 wa = *(const float4*)(wp + c * HID);
        float4 wb = *(const float4*)(wp + c * HID + 4);
        acc[0] = fmaf(wa.x, xv, acc[0]);
        acc[1] = fmaf(wa.y, xv, acc[1]);
        acc[2] = fmaf(wa.z, xv, acc[2]);
        acc[3] = fmaf(wa.w, xv, acc[3]);
        acc[4] = fmaf(wb.x, xv, acc[4]);
        acc[5] = fmaf(wb.y, xv, acc[5]);
        acc[6] = fmaf(wb.z, xv, acc[6]);
        acc[7] = fmaf(wb.w, xv, acc[7]);
    }
#pragma unroll
    for (int i = 0; i < 8; ++i) part[ch][pl][o0 + i] = acc[i];
    __syncthreads();

    if (t < 64) {
        int pl2 = t & 7, og2 = t >> 3, oo = og2 * 8;
        int p2 = tile * 8 + pl2;
        float* outp = f2o + ((size_t)b * P2 + p2) * HID + oo;
#pragma unroll
        for (int i = 0; i < 8; ++i) {
            float s = 0.f;
#pragma unroll
            for (int c = 0; c < 8; ++c) s += part[c][pl2][oo + i];
            outp[i] = fmaxf(s + b2[oo + i], 0.f);
        }
    }
}

// ------- K2: conv1 + relu + 2x-bilerp(f2) add + 11-ch coarse logits -------
// 512 thr = 32 px x 8 og x 2 c-halves(256). 600 blocks.
__global__ __launch_bounds__(512) void k2_conv1(const float* __restrict__ x,
                                                const float* __restrict__ b1,
                                                const float* __restrict__ wc,
                                                const float* __restrict__ bc,
                                                float* __restrict__ ws) {
    __shared__ float part[2][32][64];
    __shared__ float gL[32 * 65];
    const float* wt = ws + WT1_OFF;
    const float* f2 = ws + F2_OFF;
    float* lout = ws + L_OFF;
    int blk = blockIdx.x;
    int b = blk / 150, tile = blk % 150;   // 150 tiles of 32 pixels
    int t = threadIdx.x;
    int pl = t & 31;
    int og = (t >> 5) & 7;
    int ch = t >> 8;          // 0 or 1
    int o0 = og * 8;
    int c0 = ch * 256;
    int p = tile * 32 + pl;

    float acc[8];
#pragma unroll
    for (int i = 0; i < 8; ++i) acc[i] = 0.f;
    const float* xp = x + ((size_t)b * CIN + c0) * P1 + p;
    const float* wp = wt + c0 * HID + o0;
#pragma unroll 8
    for (int c = 0; c < 256; ++c) {
        float xv = xp[(size_t)c * P1];
        float4 wa = *(const float4*)(wp + c * HID);
        float4 wb = *(const float4*)(wp + c * HID + 4);
        acc[0] = fmaf(wa.x, xv, acc[0]);
        acc[1] = fmaf(wa.y, xv, acc[1]);
        acc[2] = fmaf(wa.z, xv, acc[2]);
        acc[3] = fmaf(wa.w, xv, acc[3]);
        acc[4] = fmaf(wb.x, xv, acc[4]);
        acc[5] = fmaf(wb.y, xv, acc[5]);
        acc[6] = fmaf(wb.z, xv, acc[6]);
        acc[7] = fmaf(wb.w, xv, acc[7]);
    }
#pragma unroll
    for (int i = 0; i < 8; ++i) part[ch][pl][o0 + i] = acc[i];
    __syncthreads();

    if (t < 256) {
        // sum c-halves, bias, relu, add 2x-bilerp of f2
        float sum[8];
#pragma unroll
        for (int i = 0; i < 8; ++i) sum[i] = part[0][pl][o0 + i] + part[1][pl][o0 + i];

        int y = p / W1, xq = p - y * W1;
        float sy = fmaf((float)y, 0.5f, -0.25f);
        float fy = floorf(sy);
        float ty = sy - fy;
        int y0 = max(0, min(H2 - 1, (int)fy));
        int y1 = max(0, min(H2 - 1, (int)fy + 1));
        float sx = fmaf((float)xq, 0.5f, -0.25f);
        float fx = floorf(sx);
        float tx = sx - fx;
        int x0 = max(0, min(W2 - 1, (int)fx));
        int x1 = max(0, min(W2 - 1, (int)fx + 1));
        float wy0 = 1.f - ty, wx0 = 1.f - tx;
        const float* f2b = f2 + (size_t)b * P2 * HID;
        const float* r00 = f2b + (y0 * W2 + x0) * HID + o0;
        const float* r01 = f2b + (y0 * W2 + x1) * HID + o0;
        const float* r10 = f2b + (y1 * W2 + x0) * HID + o0;
        const float* r11 = f2b + (y1 * W2 + x1) * HID + o0;
#pragma unroll
        for (int i = 0; i < 8; ++i) {
            float f1v = fmaxf(sum[i] + b1[o0 + i], 0.f);
            float v0 = r00[i] * wx0 + r01[i] * tx;
            float v1 = r10[i] * wx0 + r11[i] * tx;
            gL[pl * 65 + o0 + i] = f1v + (v0 * wy0 + v1 * ty);
        }
    }
    __syncthreads();

    if (t < 256) {
        // coarse logits: l[p][k] = sum_o wc[k][o]*g[p][o] + bc[k]
        int p2 = t & 31;
        int kg = t >> 5;                 // k1 = kg (0..7), k2 = kg+8 (valid kg<3)
        int k2i = (kg < 3) ? kg + 8 : 8; // safe index
        float l1 = bc[kg];
        float l2 = bc[k2i];
        for (int o = 0; o < HID; ++o) {
            float gv = gL[p2 * 65 + o];
            l1 = fmaf(wc[kg * HID + o], gv, l1);
            l2 = fmaf(wc[k2i * HID + o], gv, l2);
        }
        float* lrow = lout + ((size_t)b * P1 + tile * 32 + p2) * 12;
        lrow[kg] = l1;
        if (kg < 3) lrow[kg + 8] = l2;
        else if (kg == 3) lrow[11] = 0.f;   // pad slot so K4 can float4-load
    }
}

// ------- K4: 8x bilerp of logits + softmax + argmax + bbox partials -------
__global__ __launch_bounds__(256) void k4_main(float* __restrict__ out,
                                               float* __restrict__ ws) {
    __shared__ int s_cnt[9], s_x0[9], s_y0[9], s_x1[9], s_y1[9];
    const float* l = ws + L_OFF;
    int* partb = (int*)(ws + PART_OFF);
    int t = threadIdx.x;
    if (t < 9) { s_cnt[t] = 0; s_x0[t] = WF; s_y0[t] = HF; s_x1[t] = -1; s_y1[t] = -1; }
    __syncthreads();

    int fl = blockIdx.x * 256 + t;         // grid exactly covers 4*307200
    int b = fl / PF;
    int r = fl - b * PF;
    int Y = r / WF;
    int X = r - Y * WF;

    float sy = fmaf((float)Y, 0.125f, -0.4375f);
    float fy = floorf(sy);
    float ty = sy - fy;
    int y0 = max(0, min(H1 - 1, (int)fy));
    int y1 = max(0, min(H1 - 1, (int)fy + 1));
    float sx = fmaf((float)X, 0.125f, -0.4375f);
    float fx = floorf(sx);
    float tx = sx - fx;
    int x0 = max(0, min(W1 - 1, (int)fx));
    int x1 = max(0, min(W1 - 1, (int)fx + 1));
    float wy0 = 1.f - ty, wx0 = 1.f - tx;

    const float* lb = l + (size_t)b * P1 * 12;
    const float4* q00 = (const float4*)(lb + (y0 * W1 + x0) * 12);
    const float4* q01 = (const float4*)(lb + (y0 * W1 + x1) * 12);
    const float4* q10 = (const float4*)(lb + (y1 * W1 + x0) * 12);
    const float4* q11 = (const float4*)(lb + (y1 * W1 + x1) * 12);
    float l00[12], l01[12], l10[12], l11[12];
#pragma unroll
    for (int j = 0; j < 3; ++j) {
        ((float4*)l00)[j] = q00[j];
        ((float4*)l01)[j] = q01[j];
        ((float4*)l10)[j] = q10[j];
        ((float4*)l11)[j] = q11[j];
    }
    float li[11];
#pragma unroll
    for (int k = 0; k < 11; ++k) {
        float v0 = l00[k] * wx0 + l01[k] * tx;
        float v1 = l10[k] * wx0 + l11[k] * tx;
        li[k] = v0 * wy0 + v1 * ty;
    }
    int am = 0;
    float bm = li[0];
#pragma unroll
    for (int k = 1; k < 11; ++k) {
        if (li[k] > bm) { bm = li[k]; am = k; }   // strict > keeps first max
    }
    float e[11];
    float s = 0.f;
#pragma unroll
    for (int k = 0; k < 11; ++k) { e[k] = __expf(li[k] - bm); s += e[k]; }
    float rs = 1.f / s;
    size_t ob = (size_t)b * NCLS * PF + r;
#pragma unroll
    for (int k = 0; k < 11; ++k) out[ob + (size_t)k * PF] = e[k] * rs;
    out[(size_t)BN * NCLS * PF + fl] = (float)am;

    // per-wave bbox: each wave spans 64 consecutive X in a single row (640%64==0)
    int lane = t & 63;
    int X0 = X & ~63;
    for (int c = 1; c <= 9; ++c) {
        unsigned long long m = __ballot(am == c);
        if (m != 0ULL && lane == 0) {
            int ci = c - 1;
            atomicAdd(&s_cnt[ci], (int)__popcll(m));
            atomicMin(&s_x0[ci], X0 + __builtin_ctzll(m));
            atomicMax(&s_x1[ci], X0 + 63 - __builtin_clzll(m));
            atomicMin(&s_y0[ci], Y);
            atomicMax(&s_y1[ci], Y);
        }
    }
    __syncthreads();
    if (t < 9) {
        int* pr = partb + blockIdx.x * 45 + t * 5;
        pr[0] = s_cnt[t];
        pr[1] = s_x0[t];
        pr[2] = s_y0[t];
        pr[3] = s_x1[t];
        pr[4] = s_y1[t];
    }
}

// ---------------- K5: reduce bbox partials, emit rows ----------------
__global__ void k5_bbx(float* __restrict__ out, const float* __restrict__ ws) {
    const int* partb = (const int*)(ws + PART_OFF);
    int b = blockIdx.x / 9, c = blockIdx.x % 9;
    int t = threadIdx.x;  // 64
    int cnt = 0, mnx = WF, mny = HF, mxx = -1, mxy = -1;
    for (int i = t; i < 1200; i += 64) {
        const int* pr = partb + (size_t)(b * 1200 + i) * 45 + c * 5;
        cnt += pr[0];
        mnx = min(mnx, pr[1]);
        mny = min(mny, pr[2]);
        mxx = max(mxx, pr[3]);
        mxy = max(mxy, pr[4]);
    }
    for (int sft = 32; sft; sft >>= 1) {
        cnt += __shfl_xor(cnt, sft);
        mnx = min(mnx, __shfl_xor(mnx, sft));
        mny = min(mny, __shfl_xor(mny, sft));
        mxx = max(mxx, __shfl_xor(mxx, sft));
        mxy = max(mxy, __shfl_xor(mxy, sft));
    }
    if (t == 0) {
        float* row = out + (size_t)BN * NCLS * PF + (size_t)BN * PF + (size_t)(b * 9 + c) * 6;
        bool ok = cnt >= THRESH;
        row[0] = ok ? (float)b : -1.f;
        row[1] = ok ? (float)mnx : -1.f;
        row[2] = ok ? (float)mny : -1.f;
        row[3] = ok ? (float)mxx : -1.f;
        row[4] = ok ? (float)mxy : -1.f;
        row[5] = ok ? (float)(c + 1) : -1.f;
    }
}

extern "C" void kernel_launch(void* const* d_in, const int* in_sizes, int n_in,
                              void* d_out, int out_size, void* d_ws, size_t ws_size,
                              hipStream_t stream) {
    const float* f1 = (const float*)d_in[0];
    const float* f2 = (const float*)d_in[1];
    const float* w1 = (const float*)d_in[2];
    const float* b1 = (const float*)d_in[3];
    const float* w2 = (const float*)d_in[4];
    const float* b2 = (const float*)d_in[5];
    const float* wc = (const float*)d_in[6];
    const float* bc = (const float*)d_in[7];
    float* out = (float*)d_out;
    float* ws = (float*)d_ws;

    k0_init<<<dim3(256), dim3(256), 0, stream>>>(w1, w2, ws);
    k1_conv2<<<dim3(600), dim3(512), 0, stream>>>(f2, b2, ws);
    k2_conv1<<<dim3(600), dim3(512), 0, stream>>>(f1, b1, wc, bc, ws);
    k4_main<<<dim3(4800), dim3(256), 0, stream>>>(out, ws);
    k5_bbx<<<dim3(36), dim3(64), 0, stream>>>(out, ws);
}

// Round 3
// 200.324 us; speedup vs baseline: 2.3275x; 1.2989x over previous
//
#include <hip/hip_runtime.h>

#define BN 4
#define CIN 512
#define H1 60
#define W1 80
#define P1 4800
#define H2 30
#define W2 40
#define P2 1200
#define HID 64
#define NCLS 11
#define HF 480
#define WF 640
#define PF 307200
#define THRESH 500

// ws layout (float element offsets)
#define WT1_OFF 0                   // 512*64 transposed w1 [c][o]
#define WT2_OFF 32768               // 512*64 transposed w2
#define F2_OFF  65536               // 4*1200*64 post-relu f2, pixel-major [b][p][o]
#define PART_OFF F2_OFF             // k4 bbox partials alias F2 (dead by then): 4800*45 ints
#define L_OFF   (65536 + 307200)    // 372736: 4*4800*12 coarse logits [b][p][k]

// ---------------- K0: transpose weights ----------------
__global__ void k0_init(const float* __restrict__ w1, const float* __restrict__ w2,
                        float* __restrict__ ws) {
    int idx = blockIdx.x * 256 + threadIdx.x;
    if (idx < 32768) {
        int c = idx >> 6, o = idx & 63;
        ws[WT1_OFF + idx] = w1[o * CIN + c];
    } else {
        int j = idx - 32768;
        int c = j >> 6, o = j & 63;
        ws[WT2_OFF + j] = w2[o * CIN + c];
    }
}

// ---------------- K1: conv2 (512->64) + relu, pixel-major out ----------------
// 384 thr = 12 quads(48px) x 8 og x 4 ch(128c). 25 tiles/b -> grid 100.
__global__ __launch_bounds__(384, 4) void k1_conv2(const float* __restrict__ x,
                                                   const float* __restrict__ b2,
                                                   float* __restrict__ ws) {
    __shared__ float part[4 * 48 * 65];      // [ch][px*65+o], 49920 B
    const float* wt = ws + WT2_OFF;
    float* f2o = ws + F2_OFF;
    int blk = blockIdx.x;
    int b = blk / 25, tile = blk % 25;
    int t = threadIdx.x;
    int q = t % 12;
    int og = (t / 12) % 8;
    int ch = t / 96;
    int o0 = og * 8;
    int c0 = ch * 128;
    int p0 = tile * 48 + q * 4;

    float acc[4][8];
#pragma unroll
    for (int j = 0; j < 4; ++j)
#pragma unroll
        for (int i = 0; i < 8; ++i) acc[j][i] = 0.f;

    const float* xp = x + ((size_t)b * CIN + c0) * P2 + p0;
    const float* wp = wt + c0 * HID + o0;
#pragma unroll 4
    for (int c = 0; c < 128; ++c) {
        float4 xv = *(const float4*)(xp + (size_t)c * P2);
        float4 wa = *(const float4*)(wp + c * HID);
        float4 wb = *(const float4*)(wp + c * HID + 4);
        float w8[8] = {wa.x, wa.y, wa.z, wa.w, wb.x, wb.y, wb.z, wb.w};
        float x4[4] = {xv.x, xv.y, xv.z, xv.w};
#pragma unroll
        for (int j = 0; j < 4; ++j)
#pragma unroll
            for (int i = 0; i < 8; ++i) acc[j][i] = fmaf(w8[i], x4[j], acc[j][i]);
    }
#pragma unroll
    for (int j = 0; j < 4; ++j)
#pragma unroll
        for (int i = 0; i < 8; ++i)
            part[ch * 3120 + (q * 4 + j) * 65 + o0 + i] = acc[j][i];
    __syncthreads();

    // combine + bias + relu -> global, fully coalesced
    int px = t >> 3;             // 0..47
    int oo = (t & 7) * 8;
    float v[8];
#pragma unroll
    for (int i = 0; i < 8; ++i) {
        int a = px * 65 + oo + i;
        float s = part[a] + part[3120 + a] + part[2 * 3120 + a] + part[3 * 3120 + a];
        v[i] = fmaxf(s + b2[oo + i], 0.f);
    }
    float* outp = f2o + ((size_t)b * P2 + tile * 48 + px) * HID + oo;
    *(float4*)outp = make_float4(v[0], v[1], v[2], v[3]);
    *(float4*)(outp + 4) = make_float4(v[4], v[5], v[6], v[7]);
}

// ------- K2: conv1 + relu + 2x-bilerp(f2) add + 11-ch coarse logits -------
// 512 thr = 16 quads(64px) x 8 og x 4 ch(128c). 75 tiles/b -> grid 300.
__global__ __launch_bounds__(512, 4) void k2_conv1(const float* __restrict__ x,
                                                   const float* __restrict__ b1,
                                                   const float* __restrict__ wc,
                                                   const float* __restrict__ bc,
                                                   float* __restrict__ ws) {
    __shared__ float part[4 * 64 * 65];      // [ch][px*65+o], 66560 B
    const float* wt = ws + WT1_OFF;
    const float* f2 = ws + F2_OFF;
    float* lout = ws + L_OFF;
    int blk = blockIdx.x;
    int b = blk / 75, tile = blk % 75;
    int t = threadIdx.x;
    int q = t & 15;
    int og = (t >> 4) & 7;
    int ch = t >> 7;
    int o0 = og * 8;
    int c0 = ch * 128;
    int p0 = tile * 64 + q * 4;

    float acc[4][8];
#pragma unroll
    for (int j = 0; j < 4; ++j)
#pragma unroll
        for (int i = 0; i < 8; ++i) acc[j][i] = 0.f;

    const float* xp = x + ((size_t)b * CIN + c0) * P1 + p0;
    const float* wp = wt + c0 * HID + o0;
#pragma unroll 4
    for (int c = 0; c < 128; ++c) {
        float4 xv = *(const float4*)(xp + (size_t)c * P1);
        float4 wa = *(const float4*)(wp + c * HID);
        float4 wb = *(const float4*)(wp + c * HID + 4);
        float w8[8] = {wa.x, wa.y, wa.z, wa.w, wb.x, wb.y, wb.z, wb.w};
        float x4[4] = {xv.x, xv.y, xv.z, xv.w};
#pragma unroll
        for (int j = 0; j < 4; ++j)
#pragma unroll
            for (int i = 0; i < 8; ++i) acc[j][i] = fmaf(w8[i], x4[j], acc[j][i]);
    }
#pragma unroll
    for (int j = 0; j < 4; ++j)
#pragma unroll
        for (int i = 0; i < 8; ++i)
            part[ch * 4160 + (q * 4 + j) * 65 + o0 + i] = acc[j][i];
    __syncthreads();

    // combine 4 chunks + bias + relu + 2x-bilerp(f2) add; write g back into chunk 0
    {
        int px = t >> 3;             // 0..63
        int oo = (t & 7) * 8;
        int p = tile * 64 + px;
        int y = p / W1, xq = p - y * W1;
        float sy = fmaf((float)y, 0.5f, -0.25f);
        float fy = floorf(sy);
        float ty = sy - fy;
        int y0 = max(0, min(H2 - 1, (int)fy));
        int y1 = max(0, min(H2 - 1, (int)fy + 1));
        float sx = fmaf((float)xq, 0.5f, -0.25f);
        float fx = floorf(sx);
        float tx = sx - fx;
        int x0 = max(0, min(W2 - 1, (int)fx));
        int x1 = max(0, min(W2 - 1, (int)fx + 1));
        float wy0 = 1.f - ty, wx0 = 1.f - tx;
        const float* f2b = f2 + (size_t)b * P2 * HID;
        const float* r00 = f2b + (y0 * W2 + x0) * HID + oo;
        const float* r01 = f2b + (y0 * W2 + x1) * HID + oo;
        const float* r10 = f2b + (y1 * W2 + x0) * HID + oo;
        const float* r11 = f2b + (y1 * W2 + x1) * HID + oo;
#pragma unroll
        for (int i = 0; i < 8; ++i) {
            int a = px * 65 + oo + i;
            float s = part[a] + part[4160 + a] + part[2 * 4160 + a] + part[3 * 4160 + a];
            float f1v = fmaxf(s + b1[oo + i], 0.f);
            float v0 = r00[i] * wx0 + r01[i] * tx;
            float v1 = r10[i] * wx0 + r11[i] * tx;
            part[a] = f1v + (v0 * wy0 + v1 * ty);
        }
    }
    __syncthreads();

    // coarse logits: l[px][k] = sum_o wc[k][o]*g[px][o] + bc[k]
    {
        int px2 = t & 63;
        int kg = t >> 6;                 // k1 = kg (0..7), k2 = kg+8 (valid kg<3)
        int k2i = (kg < 3) ? kg + 8 : 8;
        float l1 = bc[kg];
        float l2 = bc[k2i];
#pragma unroll 8
        for (int o = 0; o < HID; ++o) {
            float gv = part[px2 * 65 + o];
            l1 = fmaf(wc[kg * HID + o], gv, l1);
            l2 = fmaf(wc[k2i * HID + o], gv, l2);
        }
        float* lrow = lout + ((size_t)b * P1 + tile * 64 + px2) * 12;
        lrow[kg] = l1;
        if (kg < 3) lrow[kg + 8] = l2;
        else if (kg == 3) lrow[11] = 0.f;   // pad slot so K4 can float4-load
    }
}

// ------- K4: 8x bilerp of logits + softmax + argmax + bbox partials -------
__global__ __launch_bounds__(256) void k4_main(float* __restrict__ out,
                                               float* __restrict__ ws) {
    __shared__ int s_cnt[9], s_x0[9], s_y0[9], s_x1[9], s_y1[9];
    const float* l = ws + L_OFF;
    int* partb = (int*)(ws + PART_OFF);
    int t = threadIdx.x;
    if (t < 9) { s_cnt[t] = 0; s_x0[t] = WF; s_y0[t] = HF; s_x1[t] = -1; s_y1[t] = -1; }
    __syncthreads();

    int fl = blockIdx.x * 256 + t;         // grid exactly covers 4*307200
    int b = fl / PF;
    int r = fl - b * PF;
    int Y = r / WF;
    int X = r - Y * WF;

    float sy = fmaf((float)Y, 0.125f, -0.4375f);
    float fy = floorf(sy);
    float ty = sy - fy;
    int y0 = max(0, min(H1 - 1, (int)fy));
    int y1 = max(0, min(H1 - 1, (int)fy + 1));
    float sx = fmaf((float)X, 0.125f, -0.4375f);
    float fx = floorf(sx);
    float tx = sx - fx;
    int x0 = max(0, min(W1 - 1, (int)fx));
    int x1 = max(0, min(W1 - 1, (int)fx + 1));
    float wy0 = 1.f - ty, wx0 = 1.f - tx;

    const float* lb = l + (size_t)b * P1 * 12;
    const float4* q00 = (const float4*)(lb + (y0 * W1 + x0) * 12);
    const float4* q01 = (const float4*)(lb + (y0 * W1 + x1) * 12);
    const float4* q10 = (const float4*)(lb + (y1 * W1 + x0) * 12);
    const float4* q11 = (const float4*)(lb + (y1 * W1 + x1) * 12);
    float l00[12], l01[12], l10[12], l11[12];
#pragma unroll
    for (int j = 0; j < 3; ++j) {
        ((float4*)l00)[j] = q00[j];
        ((float4*)l01)[j] = q01[j];
        ((float4*)l10)[j] = q10[j];
        ((float4*)l11)[j] = q11[j];
    }
    float li[11];
#pragma unroll
    for (int k = 0; k < 11; ++k) {
        float v0 = l00[k] * wx0 + l01[k] * tx;
        float v1 = l10[k] * wx0 + l11[k] * tx;
        li[k] = v0 * wy0 + v1 * ty;
    }
    int am = 0;
    float bm = li[0];
#pragma unroll
    for (int k = 1; k < 11; ++k) {
        if (li[k] > bm) { bm = li[k]; am = k; }   // strict > keeps first max
    }
    float e[11];
    float s = 0.f;
#pragma unroll
    for (int k = 0; k < 11; ++k) { e[k] = __expf(li[k] - bm); s += e[k]; }
    float rs = 1.f / s;
    size_t ob = (size_t)b * NCLS * PF + r;
#pragma unroll
    for (int k = 0; k < 11; ++k) out[ob + (size_t)k * PF] = e[k] * rs;
    out[(size_t)BN * NCLS * PF + fl] = (float)am;

    // per-wave bbox: each wave spans 64 consecutive X in a single row (640%64==0)
    int lane = t & 63;
    int X0 = X & ~63;
    for (int c = 1; c <= 9; ++c) {
        unsigned long long m = __ballot(am == c);
        if (m != 0ULL && lane == 0) {
            int ci = c - 1;
            atomicAdd(&s_cnt[ci], (int)__popcll(m));
            atomicMin(&s_x0[ci], X0 + __builtin_ctzll(m));
            atomicMax(&s_x1[ci], X0 + 63 - __builtin_clzll(m));
            atomicMin(&s_y0[ci], Y);
            atomicMax(&s_y1[ci], Y);
        }
    }
    __syncthreads();
    if (t < 9) {
        int* pr = partb + blockIdx.x * 45 + t * 5;
        pr[0] = s_cnt[t];
        pr[1] = s_x0[t];
        pr[2] = s_y0[t];
        pr[3] = s_x1[t];
        pr[4] = s_y1[t];
    }
}

// ---------------- K5: reduce bbox partials, emit rows ----------------
__global__ void k5_bbx(float* __restrict__ out, const float* __restrict__ ws) {
    const int* partb = (const int*)(ws + PART_OFF);
    int b = blockIdx.x / 9, c = blockIdx.x % 9;
    int t = threadIdx.x;  // 64
    int cnt = 0, mnx = WF, mny = HF, mxx = -1, mxy = -1;
    for (int i = t; i < 1200; i += 64) {
        const int* pr = partb + (size_t)(b * 1200 + i) * 45 + c * 5;
        cnt += pr[0];
        mnx = min(mnx, pr[1]);
        mny = min(mny, pr[2]);
        mxx = max(mxx, pr[3]);
        mxy = max(mxy, pr[4]);
    }
    for (int sft = 32; sft; sft >>= 1) {
        cnt += __shfl_xor(cnt, sft);
        mnx = min(mnx, __shfl_xor(mnx, sft));
        mny = min(mny, __shfl_xor(mny, sft));
        mxx = max(mxx, __shfl_xor(mxx, sft));
        mxy = max(mxy, __shfl_xor(mxy, sft));
    }
    if (t == 0) {
        float* row = out + (size_t)BN * NCLS * PF + (size_t)BN * PF + (size_t)(b * 9 + c) * 6;
        bool ok = cnt >= THRESH;
        row[0] = ok ? (float)b : -1.f;
        row[1] = ok ? (float)mnx : -1.f;
        row[2] = ok ? (float)mny : -1.f;
        row[3] = ok ? (float)mxx : -1.f;
        row[4] = ok ? (float)mxy : -1.f;
        row[5] = ok ? (float)(c + 1) : -1.f;
    }
}

extern "C" void kernel_launch(void* const* d_in, const int* in_sizes, int n_in,
                              void* d_out, int out_size, void* d_ws, size_t ws_size,
                              hipStream_t stream) {
    const float* f1 = (const float*)d_in[0];
    const float* f2 = (const float*)d_in[1];
    const float* w1 = (const float*)d_in[2];
    const float* b1 = (const float*)d_in[3];
    const float* w2 = (const float*)d_in[4];
    const float* b2 = (const float*)d_in[5];
    const float* wc = (const float*)d_in[6];
    const float* bc = (const float*)d_in[7];
    float* out = (float*)d_out;
    float* ws = (float*)d_ws;

    k0_init<<<dim3(256), dim3(256), 0, stream>>>(w1, w2, ws);
    k1_conv2<<<dim3(100), dim3(384), 0, stream>>>(f2, b2, ws);
    k2_conv1<<<dim3(300), dim3(512), 0, stream>>>(f1, b1, wc, bc, ws);
    k4_main<<<dim3(4800), dim3(256), 0, stream>>>(out, ws);
    k5_bbx<<<dim3(36), dim3(64), 0, stream>>>(out, ws);
}

// Round 5
// 169.559 us; speedup vs baseline: 2.7498x; 1.1814x over previous
//
#include <hip/hip_runtime.h>

#define BN 4
#define CIN 512
#define H1 60
#define W1 80
#define P1 4800
#define H2 30
#define W2 40
#define P2 1200
#define HID 64
#define NCLS 11
#define HF 480
#define WF 640
#define PF 307200
#define THRESH 500

// ws layout (float element offsets)
#define WT1_OFF 0                   // 512*64 transposed w1 [c][o]
#define WT2_OFF 32768               // 512*64 transposed w2
#define F2_OFF  65536               // 4*1200*64 post-relu f2, pixel-major [b][p][o]
#define PART_OFF F2_OFF             // k4 bbox partials alias F2 (dead by then): 4800*45 ints
#define L_OFF   (65536 + 307200)    // 372736: 4*4800*12 coarse logits [b][p][k]

__device__ __forceinline__ void dma16(const float* g, float* l) {
    __builtin_amdgcn_global_load_lds(
        (const __attribute__((address_space(1))) void*)g,
        (__attribute__((address_space(3))) void*)l, 16, 0, 0);
}

// ---------------- K0: transpose weights ----------------
__global__ void k0_init(const float* __restrict__ w1, const float* __restrict__ w2,
                        float* __restrict__ ws) {
    int idx = blockIdx.x * 256 + threadIdx.x;
    if (idx < 32768) {
        int c = idx >> 6, o = idx & 63;
        ws[WT1_OFF + idx] = w1[o * CIN + c];
    } else {
        int j = idx - 32768;
        int c = j >> 6, o = j & 63;
        ws[WT2_OFF + j] = w2[o * CIN + c];
    }
}

// ---------------- K1: conv2 (512->64) + relu, pixel-major out ----------------
// 256 thr = 4 quads(16px) x 8 og x 8 ch(64c). grid 4*75=300.
// x staged via global_load_lds double-buffer: 2 steps of 32c across 8 chunks.
__global__ __launch_bounds__(256, 4) void k1_conv2(const float* __restrict__ x,
                                                   const float* __restrict__ b2,
                                                   float* __restrict__ ws) {
    __shared__ float lds[8320];   // union: stage[2][4096] | partials[8][16][65]
    const float* wt = ws + WT2_OFF;
    float* f2o = ws + F2_OFF;
    int blk = blockIdx.x;
    int b = blk / 75, tile = blk % 75;
    int t = threadIdx.x;
    int l = t & 63, w = t >> 6;
    int q = t & 3, og = (t >> 2) & 7, ch = t >> 5;
    int o0 = og * 8;
    int p0 = tile * 16;
    const float* xb = x + (size_t)b * CIN * P2 + p0;

    auto stage = [&](int s) {
        int buf = s & 1;
#pragma unroll
        for (int j = 0; j < 4; ++j) {
            int r0 = j * 64 + w * 16;          // wave-uniform; rows r0..r0+15
            int r  = r0 + (l >> 2);            // row this lane fills
            int cg = (r >> 5) * 64 + s * 32 + (r & 31);   // chunk*64 + step c
            dma16(xb + (size_t)cg * P2 + (l & 3) * 4,
                  lds + buf * 4096 + r0 * 16);
        }
    };

    float acc[4][8];
#pragma unroll
    for (int j = 0; j < 4; ++j)
#pragma unroll
        for (int i = 0; i < 8; ++i) acc[j][i] = 0.f;

    stage(0);
    __syncthreads();
    const float* wp = wt + (ch * 64) * HID + o0;
    for (int s = 0; s < 2; ++s) {
        if (s < 1) stage(s + 1);
        const float* xs = lds + (s & 1) * 4096 + ch * 512 + q * 4;
#pragma unroll 4
        for (int cc = 0; cc < 32; ++cc) {
            float4 xv = *(const float4*)(xs + cc * 16);
            const float* wr = wp + (s * 32 + cc) * HID;
            float4 wa = *(const float4*)(wr);
            float4 wb = *(const float4*)(wr + 4);
            float w8[8] = {wa.x, wa.y, wa.z, wa.w, wb.x, wb.y, wb.z, wb.w};
            float x4[4] = {xv.x, xv.y, xv.z, xv.w};
#pragma unroll
            for (int j = 0; j < 4; ++j)
#pragma unroll
                for (int i = 0; i < 8; ++i) acc[j][i] = fmaf(w8[i], x4[j], acc[j][i]);
        }
        __syncthreads();
    }
#pragma unroll
    for (int j = 0; j < 4; ++j)
#pragma unroll
        for (int i = 0; i < 8; ++i)
            lds[ch * 1040 + (q * 4 + j) * 65 + o0 + i] = acc[j][i];
    __syncthreads();

    if (t < 128) {
        int px = t >> 3, oo = (t & 7) * 8;
        float v[8];
#pragma unroll
        for (int i = 0; i < 8; ++i) {
            float s = 0.f;
#pragma unroll
            for (int c = 0; c < 8; ++c) s += lds[c * 1040 + px * 65 + oo + i];
            v[i] = fmaxf(s + b2[oo + i], 0.f);
        }
        float* outp = f2o + ((size_t)b * P2 + p0 + px) * HID + oo;
        *(float4*)outp = make_float4(v[0], v[1], v[2], v[3]);
        *(float4*)(outp + 4) = make_float4(v[4], v[5], v[6], v[7]);
    }
}

// ------- K2: conv1 + relu + 2x-bilerp(f2) add + 11-ch coarse logits -------
// 256 thr = 8 quads(32px) x 8 og x 4 ch(128c). grid 4*150=600.
// x staged via global_load_lds double-buffer: 4 steps of 32c across 4 chunks.
__global__ __launch_bounds__(256, 4) void k2_conv1(const float* __restrict__ x,
                                                   const float* __restrict__ b1,
                                                   const float* __restrict__ wc,
                                                   const float* __restrict__ bc,
                                                   float* __restrict__ ws) {
    __shared__ float lds[8320];   // union: stage[2][4096] | partials[4][32][65]
    const float* wt = ws + WT1_OFF;
    const float* f2 = ws + F2_OFF;
    float* lout = ws + L_OFF;
    int blk = blockIdx.x;
    int b = blk / 150, tile = blk % 150;
    int t = threadIdx.x;
    int l = t & 63, w = t >> 6;
    int q = t & 7, og = (t >> 3) & 7, ch = t >> 6;   // ch == wave id
    int o0 = og * 8;
    int p0 = tile * 32;
    const float* xb = x + (size_t)b * CIN * P1 + p0;

    auto stage = [&](int s) {
        int buf = s & 1;
#pragma unroll
        for (int j = 0; j < 4; ++j) {
            int r0 = j * 32 + w * 8;           // wave-uniform; rows r0..r0+7
            int r  = r0 + (l >> 3);
            int cg = (r >> 5) * 128 + s * 32 + (r & 31);  // chunk*128 + step c
            dma16(xb + (size_t)cg * P1 + (l & 7) * 4,
                  lds + buf * 4096 + r0 * 32);
        }
    };

    float acc[4][8];
#pragma unroll
    for (int j = 0; j < 4; ++j)
#pragma unroll
        for (int i = 0; i < 8; ++i) acc[j][i] = 0.f;

    stage(0);
    __syncthreads();
    const float* wp = wt + (ch * 128) * HID + o0;
    for (int s = 0; s < 4; ++s) {          // 4 steps x 32c = 128c per chunk
        if (s < 3) stage(s + 1);
        const float* xs = lds + (s & 1) * 4096 + ch * 1024 + q * 4;
#pragma unroll 4
        for (int cc = 0; cc < 32; ++cc) {
            float4 xv = *(const float4*)(xs + cc * 32);
            const float* wr = wp + (s * 32 + cc) * HID;
            float4 wa = *(const float4*)(wr);
            float4 wb = *(const float4*)(wr + 4);
            float w8[8] = {wa.x, wa.y, wa.z, wa.w, wb.x, wb.y, wb.z, wb.w};
            float x4[4] = {xv.x, xv.y, xv.z, xv.w};
#pragma unroll
            for (int j = 0; j < 4; ++j)
#pragma unroll
                for (int i = 0; i < 8; ++i) acc[j][i] = fmaf(w8[i], x4[j], acc[j][i]);
        }
        __syncthreads();
    }
#pragma unroll
    for (int j = 0; j < 4; ++j)
#pragma unroll
        for (int i = 0; i < 8; ++i)
            lds[ch * 2080 + (q * 4 + j) * 65 + o0 + i] = acc[j][i];
    __syncthreads();

    // combine 4 chunks + bias + relu + 2x-bilerp(f2) add; g -> lds[px*65+o]
    {
        int px = t >> 3;             // 0..31
        int oo = (t & 7) * 8;
        int p = p0 + px;
        int y = p / W1, xq = p - y * W1;
        float sy = fmaf((float)y, 0.5f, -0.25f);
        float fy = floorf(sy);
        float ty = sy - fy;
        int y0 = max(0, min(H2 - 1, (int)fy));
        int y1 = max(0, min(H2 - 1, (int)fy + 1));
        float sx = fmaf((float)xq, 0.5f, -0.25f);
        float fx = floorf(sx);
        float tx = sx - fx;
        int x0 = max(0, min(W2 - 1, (int)fx));
        int x1 = max(0, min(W2 - 1, (int)fx + 1));
        float wy0 = 1.f - ty, wx0 = 1.f - tx;
        const float* f2b = f2 + (size_t)b * P2 * HID;
        const float* r00 = f2b + (y0 * W2 + x0) * HID + oo;
        const float* r01 = f2b + (y0 * W2 + x1) * HID + oo;
        const float* r10 = f2b + (y1 * W2 + x0) * HID + oo;
        const float* r11 = f2b + (y1 * W2 + x1) * HID + oo;
#pragma unroll
        for (int i = 0; i < 8; ++i) {
            int a = px * 65 + oo + i;
            float s = lds[a] + lds[2080 + a] + lds[2 * 2080 + a] + lds[3 * 2080 + a];
            float f1v = fmaxf(s + b1[oo + i], 0.f);
            float v0 = r00[i] * wx0 + r01[i] * tx;
            float v1 = r10[i] * wx0 + r11[i] * tx;
            lds[a] = f1v + (v0 * wy0 + v1 * ty);
        }
    }
    __syncthreads();

    // coarse logits: l[px][k] = sum_o wc[k][o]*g[px][o] + bc[k]
    {
        int px2 = t & 31;
        int kg = t >> 5;                 // 0..7; second class kg+8 valid for kg<3
        int k2i = (kg < 3) ? kg + 8 : 8;
        float l1 = bc[kg];
        float l2 = bc[k2i];
#pragma unroll 8
        for (int o = 0; o < HID; ++o) {
            float gv = lds[px2 * 65 + o];
            l1 = fmaf(wc[kg * HID + o], gv, l1);
            l2 = fmaf(wc[k2i * HID + o], gv, l2);
        }
        float* lrow = lout + ((size_t)b * P1 + p0 + px2) * 12;
        lrow[kg] = l1;
        if (kg < 3) lrow[kg + 8] = l2;
        else if (kg == 3) lrow[11] = 0.f;   // pad slot so K4 can float4-load
    }
}

// ------- K4: 8x bilerp of logits + softmax + argmax + bbox partials -------
__global__ __launch_bounds__(256) void k4_main(float* __restrict__ out,
                                               float* __restrict__ ws) {
    __shared__ int s_cnt[9], s_x0[9], s_y0[9], s_x1[9], s_y1[9];
    const float* l = ws + L_OFF;
    int* partb = (int*)(ws + PART_OFF);
    int t = threadIdx.x;
    if (t < 9) { s_cnt[t] = 0; s_x0[t] = WF; s_y0[t] = HF; s_x1[t] = -1; s_y1[t] = -1; }
    __syncthreads();

    int fl = blockIdx.x * 256 + t;         // grid exactly covers 4*307200
    int b = fl / PF;
    int r = fl - b * PF;
    int Y = r / WF;
    int X = r - Y * WF;

    float sy = fmaf((float)Y, 0.125f, -0.4375f);
    float fy = floorf(sy);
    float ty = sy - fy;
    int y0 = max(0, min(H1 - 1, (int)fy));
    int y1 = max(0, min(H1 - 1, (int)fy + 1));
    float sx = fmaf((float)X, 0.125f, -0.4375f);
    float fx = floorf(sx);
    float tx = sx - fx;
    int x0 = max(0, min(W1 - 1, (int)fx));
    int x1 = max(0, min(W1 - 1, (int)fx + 1));
    float wy0 = 1.f - ty, wx0 = 1.f - tx;

    const float* lb = l + (size_t)b * P1 * 12;
    const float4* q00 = (const float4*)(lb + (y0 * W1 + x0) * 12);
    const float4* q01 = (const float4*)(lb + (y0 * W1 + x1) * 12);
    const float4* q10 = (const float4*)(lb + (y1 * W1 + x0) * 12);
    const float4* q11 = (const float4*)(lb + (y1 * W1 + x1) * 12);
    float l00[12], l01[12], l10[12], l11[12];
#pragma unroll
    for (int j = 0; j < 3; ++j) {
        ((float4*)l00)[j] = q00[j];
        ((float4*)l01)[j] = q01[j];
        ((float4*)l10)[j] = q10[j];
        ((float4*)l11)[j] = q11[j];
    }
    float li[11];
#pragma unroll
    for (int k = 0; k < 11; ++k) {
        float v0 = l00[k] * wx0 + l01[k] * tx;
        float v1 = l10[k] * wx0 + l11[k] * tx;
        li[k] = v0 * wy0 + v1 * ty;
    }
    int am = 0;
    float bm = li[0];
#pragma unroll
    for (int k = 1; k < 11; ++k) {
        if (li[k] > bm) { bm = li[k]; am = k; }   // strict > keeps first max
    }
    float e[11];
    float s = 0.f;
#pragma unroll
    for (int k = 0; k < 11; ++k) { e[k] = __expf(li[k] - bm); s += e[k]; }
    float rs = 1.f / s;
    size_t ob = (size_t)b * NCLS * PF + r;
#pragma unroll
    for (int k = 0; k < 11; ++k) out[ob + (size_t)k * PF] = e[k] * rs;
    out[(size_t)BN * NCLS * PF + fl] = (float)am;

    // per-wave bbox: each wave spans 64 consecutive X in a single row (640%64==0)
    int lane = t & 63;
    int X0 = X & ~63;
    for (int c = 1; c <= 9; ++c) {
        unsigned long long m = __ballot(am == c);
        if (m != 0ULL && lane == 0) {
            int ci = c - 1;
            atomicAdd(&s_cnt[ci], (int)__popcll(m));
            atomicMin(&s_x0[ci], X0 + __builtin_ctzll(m));
            atomicMax(&s_x1[ci], X0 + 63 - __builtin_clzll(m));
            atomicMin(&s_y0[ci], Y);
            atomicMax(&s_y1[ci], Y);
        }
    }
    __syncthreads();
    if (t < 9) {
        int* pr = partb + blockIdx.x * 45 + t * 5;
        pr[0] = s_cnt[t];
        pr[1] = s_x0[t];
        pr[2] = s_y0[t];
        pr[3] = s_x1[t];
        pr[4] = s_y1[t];
    }
}

// ---------------- K5: reduce bbox partials, emit rows ----------------
__global__ void k5_bbx(float* __restrict__ out, const float* __restrict__ ws) {
    const int* partb = (const int*)(ws + PART_OFF);
    int b = blockIdx.x / 9, c = blockIdx.x % 9;
    int t = threadIdx.x;  // 64
    int cnt = 0, mnx = WF, mny = HF, mxx = -1, mxy = -1;
    for (int i = t; i < 1200; i += 64) {
        const int* pr = partb + (size_t)(b * 1200 + i) * 45 + c * 5;
        cnt += pr[0];
        mnx = min(mnx, pr[1]);
        mny = min(mny, pr[2]);
        mxx = max(mxx, pr[3]);
        mxy = max(mxy, pr[4]);
    }
    for (int sft = 32; sft; sft >>= 1) {
        cnt += __shfl_xor(cnt, sft);
        mnx = min(mnx, __shfl_xor(mnx, sft));
        mny = min(mny, __shfl_xor(mny, sft));
        mxx = max(mxx, __shfl_xor(mxx, sft));
        mxy = max(mxy, __shfl_xor(mxy, sft));
    }
    if (t == 0) {
        float* row = out + (size_t)BN * NCLS * PF + (size_t)BN * PF + (size_t)(b * 9 + c) * 6;
        bool ok = cnt >= THRESH;
        row[0] = ok ? (float)b : -1.f;
        row[1] = ok ? (float)mnx : -1.f;
        row[2] = ok ? (float)mny : -1.f;
        row[3] = ok ? (float)mxx : -1.f;
        row[4] = ok ? (float)mxy : -1.f;
        row[5] = ok ? (float)(c + 1) : -1.f;
    }
}

extern "C" void kernel_launch(void* const* d_in, const int* in_sizes, int n_in,
                              void* d_out, int out_size, void* d_ws, size_t ws_size,
                              hipStream_t stream) {
    const float* f1 = (const float*)d_in[0];
    const float* f2 = (const float*)d_in[1];
    const float* w1 = (const float*)d_in[2];
    const float* b1 = (const float*)d_in[3];
    const float* w2 = (const float*)d_in[4];
    const float* b2 = (const float*)d_in[5];
    const float* wc = (const float*)d_in[6];
    const float* bc = (const float*)d_in[7];
    float* out = (float*)d_out;
    float* ws = (float*)d_ws;

    k0_init<<<dim3(256), dim3(256), 0, stream>>>(w1, w2, ws);
    k1_conv2<<<dim3(300), dim3(256), 0, stream>>>(f2, b2, ws);
    k2_conv1<<<dim3(600), dim3(256), 0, stream>>>(f1, b1, wc, bc, ws);
    k4_main<<<dim3(4800), dim3(256), 0, stream>>>(out, ws);
    k5_bbx<<<dim3(36), dim3(64), 0, stream>>>(out, ws);
}